// Round 6
// baseline (404.150 us; speedup 1.0000x reference)
//
#include <hip/hip_runtime.h>

#define BM 128
#define BN 128
#define BKH 32   // K-half; one barrier pair covers 2 halves (BK=64)

typedef __bf16 bf16x8 __attribute__((ext_vector_type(8)));
typedef __bf16 bf16x4 __attribute__((ext_vector_type(4)));
typedef float f32x4 __attribute__((ext_vector_type(4)));
typedef __bf16 bf16_t;

__device__ __forceinline__ void gl_lds16(const void* g, void* l) {
    __builtin_amdgcn_global_load_lds(
        (const __attribute__((address_space(1))) void*)g,
        (__attribute__((address_space(3))) void*)l, 16, 0, 0);
}

// fp32 -> bf16 conversion, 4 elems/thread (n multiple of 4)
__global__ __launch_bounds__(256)
void cvt_kernel(const float* __restrict__ in, bf16_t* __restrict__ out, int n)
{
    const int i = (blockIdx.x * 256 + threadIdx.x) * 4;
    if (i < n) {
        const float4 v = *(const float4*)(in + i);
        bf16x4 o;
        o[0] = (__bf16)v.x; o[1] = (__bf16)v.y;
        o[2] = (__bf16)v.z; o[3] = (__bf16)v.w;
        *(bf16x4*)(out + i) = o;
    }
}

// Generic NT GEMM: C[m,n] = sum_k A[m,k] * Bw[n,k]  (+ epilogue per MODE)
// MODE 0: QKV fused over z: z=0 -> Wq/bq; z=1 -> Wk/bk; z=2 -> Wv/bv transposed
// MODE 2: acc + (rel==1?d1[m]:0) -> bf16 (scale+mask applied in softmax)
// MODE 3: plain bf16 store (PV), batched z
// MODE 4: + bias[n] + resid[m,n], bf16 out              [out-proj + residual]
// SWIZ=1: 1D x-grid, grouped decode (GM=8) so blocks with pid%8==c (same XCD)
// share ONE A-tile and walk n — keeps the A working set L2-resident per XCD.
// SWIZ=0: plain 2D (blockIdx.x = n-tile, blockIdx.y = m-tile)   [scores]
// K-loop: BK=64 per barrier pair, staged as two BK=32 halves (A0/A1, B0/B1).
template <int MODE, int SWIZ>
__global__ __launch_bounds__(256)
void gemm_bt(const bf16_t* __restrict__ A, const bf16_t* __restrict__ Bw,
             const float* __restrict__ bias, const float* __restrict__ bias2,
             const float* __restrict__ bias3,
             bf16_t* __restrict__ C, bf16_t* __restrict__ C2,
             int M, int N, int K,
             long long sAz, long long sBz, long long sCz,
             const int* __restrict__ rel, const float* __restrict__ d1,
             const float* __restrict__ resid,
             int Sdim, int DHdim)
{
    const int bz = blockIdx.z;
    const float* bi = bias;
    if (MODE == 0) {
        Bw += (long long)bz * N * K;        // Wq | Wk | Wv contiguous
        bi = (bz == 0) ? bias : (bz == 1 ? bias2 : bias3);
        if (bz < 2) C += (long long)bz * sCz;
    } else {
        A += (long long)bz * sAz;
        Bw += (long long)bz * sBz;
        C += (long long)bz * sCz;
    }

    int m0, n0;
    if (SWIZ) {
        const int num_n = N / BN;
        const int pid = blockIdx.x;
        const int group = 8 * num_n;         // 8 m-tiles per group
        const int g = pid / group;
        m0 = (g * 8 + (pid % 8)) * BM;
        n0 = ((pid % group) / 8) * BN;
    } else {
        m0 = blockIdx.y * BM;
        n0 = blockIdx.x * BN;
    }
    const int tid = threadIdx.x;
    const int w = tid >> 6;          // wave id 0..3
    const int lane = tid & 63;
    const int wr = w >> 1;           // wave row (2x2 wave grid, 64x64 each)
    const int wc = w & 1;
    const int srow = lane >> 2;      // staging: row within 16-row slice
    const int scol = (lane & 3) * 8; // staging: bf16 col offset (16B chunks)
    const int frow = lane & 15;      // fragment m/n index
    const int fk = (lane >> 4) * 8;  // fragment k base

    __shared__ bf16_t smem[4 * BM * BKH];   // 32 KB: A0 | A1 | B0 | B1
    bf16_t* A0 = smem;
    bf16_t* A1 = smem + BM * BKH;
    bf16_t* B0 = smem + 2 * BM * BKH;
    bf16_t* B1 = smem + 3 * BM * BKH;

    f32x4 acc[4][4];
#pragma unroll
    for (int i = 0; i < 4; ++i)
#pragma unroll
        for (int j = 0; j < 4; ++j) acc[i][j] = (f32x4)0.0f;

    for (int k0 = 0; k0 < K; k0 += 2 * BKH) {
#pragma unroll
        for (int i = 0; i < 2; ++i) {
            const int r = i * 64 + w * 16;
            const bf16_t* ga = A + (size_t)(m0 + r + srow) * K + (k0 + scol);
            const bf16_t* gb = Bw + (size_t)(n0 + r + srow) * K + (k0 + scol);
            gl_lds16(ga,        &A0[r * BKH]);
            gl_lds16(ga + BKH,  &A1[r * BKH]);
            gl_lds16(gb,        &B0[r * BKH]);
            gl_lds16(gb + BKH,  &B1[r * BKH]);
        }
        __syncthreads();
#pragma unroll
        for (int h = 0; h < 2; ++h) {
            const bf16_t* Ah = h ? A1 : A0;
            const bf16_t* Bh = h ? B1 : B0;
            bf16x8 af[4], bfv[4];
#pragma unroll
            for (int t = 0; t < 4; ++t) {
                af[t]  = *(const bf16x8*)&Ah[(wr * 64 + t * 16 + frow) * BKH + fk];
                bfv[t] = *(const bf16x8*)&Bh[(wc * 64 + t * 16 + frow) * BKH + fk];
            }
#pragma unroll
            for (int mt = 0; mt < 4; ++mt)
#pragma unroll
                for (int nt = 0; nt < 4; ++nt)
                    acc[mt][nt] = __builtin_amdgcn_mfma_f32_16x16x32_bf16(
                        af[mt], bfv[nt], acc[mt][nt], 0, 0, 0);
        }
        __syncthreads();
    }
    // After the final __syncthreads all LDS reads are drained; smem reusable.

    // C/D layout: col = lane&15, row = (lane>>4)*4 + reg
    const int crow = (lane >> 4) * 4;
    const int ccol = lane & 15;

    if (MODE == 0 && bz == 2) {
        // V projection: transposed store vT[b][n][s]
#pragma unroll
        for (int mt = 0; mt < 4; ++mt) {
            const int mb = m0 + wr * 64 + mt * 16 + crow;
#pragma unroll
            for (int nt = 0; nt < 4; ++nt) {
                const int n = n0 + wc * 64 + nt * 16 + ccol;
                const float bv = bi[n];
                const int b = mb >> 11;      // S = 2048 tokens per batch
                const int s = mb & 2047;
                union { ushort4 u; bf16_t h[4]; } pk;
#pragma unroll
                for (int r = 0; r < 4; ++r) pk.h[r] = (__bf16)(acc[mt][nt][r] + bv);
                *(ushort4*)&C2[(size_t)b * DHdim * Sdim + (size_t)n * Sdim + s] = pk.u;
            }
        }
        return;
    }

    // ---- transpose epilogue ----
    // per-wave private scratch: 16 rows x 72 cols bf16 (2304 B) -> 4 waves = 9216 B
    bf16_t* tw = smem + w * (16 * 72);
    const int r0 = lane >> 3;            // 0..7 : row within 16-slice
    const int cseg = (lane & 7) * 8;     // 8-col segment base

    float bv[4];
    if (MODE == 0 || MODE == 4) {
#pragma unroll
        for (int nt = 0; nt < 4; ++nt)
            bv[nt] = bi[n0 + wc * 64 + nt * 16 + ccol];
    }

#pragma unroll
    for (int mt = 0; mt < 4; ++mt) {
        // scatter this wave's 16x64 slice into LDS (same-wave DS is in-order)
#pragma unroll
        for (int nt = 0; nt < 4; ++nt) {
            const float badd = (MODE == 0 || MODE == 4) ? bv[nt] : 0.0f;
#pragma unroll
            for (int r = 0; r < 4; ++r)
                tw[(crow + r) * 72 + nt * 16 + ccol] = (__bf16)(acc[mt][nt][r] + badd);
        }
        bf16x8 va = *(const bf16x8*)&tw[r0 * 72 + cseg];
        bf16x8 vb = *(const bf16x8*)&tw[(r0 + 8) * 72 + cseg];

        const int gm_a = m0 + wr * 64 + mt * 16 + r0;
        const int gm_b = gm_a + 8;
        const int gn = n0 + wc * 64 + cseg;

        if (MODE == 0 || MODE == 3) {
            *(bf16x8*)&C[(size_t)gm_a * N + gn] = va;
            *(bf16x8*)&C[(size_t)gm_b * N + gn] = vb;
        } else if (MODE == 2) {
            const long long ra = ((long long)bz * M + gm_a) * N + gn;
            const long long rb = ((long long)bz * M + gm_b) * N + gn;
            const int4 ra0 = *(const int4*)&rel[ra];
            const int4 ra1 = *(const int4*)&rel[ra + 4];
            const int4 rb0 = *(const int4*)&rel[rb];
            const int4 rb1 = *(const int4*)&rel[rb + 4];
            const float da = d1[(size_t)bz * M + gm_a];
            const float db = d1[(size_t)bz * M + gm_b];
            bf16x8 oa, ob;
            oa[0] = (__bf16)((float)va[0] + (ra0.x == 1 ? da : 0.0f));
            oa[1] = (__bf16)((float)va[1] + (ra0.y == 1 ? da : 0.0f));
            oa[2] = (__bf16)((float)va[2] + (ra0.z == 1 ? da : 0.0f));
            oa[3] = (__bf16)((float)va[3] + (ra0.w == 1 ? da : 0.0f));
            oa[4] = (__bf16)((float)va[4] + (ra1.x == 1 ? da : 0.0f));
            oa[5] = (__bf16)((float)va[5] + (ra1.y == 1 ? da : 0.0f));
            oa[6] = (__bf16)((float)va[6] + (ra1.z == 1 ? da : 0.0f));
            oa[7] = (__bf16)((float)va[7] + (ra1.w == 1 ? da : 0.0f));
            ob[0] = (__bf16)((float)vb[0] + (rb0.x == 1 ? db : 0.0f));
            ob[1] = (__bf16)((float)vb[1] + (rb0.y == 1 ? db : 0.0f));
            ob[2] = (__bf16)((float)vb[2] + (rb0.z == 1 ? db : 0.0f));
            ob[3] = (__bf16)((float)vb[3] + (rb0.w == 1 ? db : 0.0f));
            ob[4] = (__bf16)((float)vb[4] + (rb1.x == 1 ? db : 0.0f));
            ob[5] = (__bf16)((float)vb[5] + (rb1.y == 1 ? db : 0.0f));
            ob[6] = (__bf16)((float)vb[6] + (rb1.z == 1 ? db : 0.0f));
            ob[7] = (__bf16)((float)vb[7] + (rb1.w == 1 ? db : 0.0f));
            *(bf16x8*)&C[(size_t)gm_a * N + gn] = oa;
            *(bf16x8*)&C[(size_t)gm_b * N + gn] = ob;
        } else {  // MODE 4: + residual, bf16 out
            const float4 xa0 = *(const float4*)&resid[(size_t)gm_a * N + gn];
            const float4 xa1 = *(const float4*)&resid[(size_t)gm_a * N + gn + 4];
            const float4 xb0 = *(const float4*)&resid[(size_t)gm_b * N + gn];
            const float4 xb1 = *(const float4*)&resid[(size_t)gm_b * N + gn + 4];
            bf16x8 oa, ob;
            oa[0] = (__bf16)((float)va[0] + xa0.x);
            oa[1] = (__bf16)((float)va[1] + xa0.y);
            oa[2] = (__bf16)((float)va[2] + xa0.z);
            oa[3] = (__bf16)((float)va[3] + xa0.w);
            oa[4] = (__bf16)((float)va[4] + xa1.x);
            oa[5] = (__bf16)((float)va[5] + xa1.y);
            oa[6] = (__bf16)((float)va[6] + xa1.z);
            oa[7] = (__bf16)((float)va[7] + xa1.w);
            ob[0] = (__bf16)((float)vb[0] + xb0.x);
            ob[1] = (__bf16)((float)vb[1] + xb0.y);
            ob[2] = (__bf16)((float)vb[2] + xb0.z);
            ob[3] = (__bf16)((float)vb[3] + xb0.w);
            ob[4] = (__bf16)((float)vb[4] + xb1.x);
            ob[5] = (__bf16)((float)vb[5] + xb1.y);
            ob[6] = (__bf16)((float)vb[6] + xb1.z);
            ob[7] = (__bf16)((float)vb[7] + xb1.w);
            *(bf16x8*)&C[(size_t)gm_a * N + gn] = oa;
            *(bf16x8*)&C[(size_t)gm_b * N + gn] = ob;
        }
    }
}

// d1[m] = sum_k q_bf16[m,k] * dist_emb_f32[1,k]  — one wave per row
__global__ __launch_bounds__(256)
void d1_kernel(const bf16_t* __restrict__ q, const float* __restrict__ de,
               float* __restrict__ d1, int H)
{
    const int row = blockIdx.x * 4 + (threadIdx.x >> 6);
    const int lane = threadIdx.x & 63;
    const bf16_t* qr = q + (size_t)row * H;
    const float* d1r = de + H;   // dist_emb row 1
    float s = 0.0f;
    for (int k = lane; k < H; k += 64)
        s += (float)qr[k] * d1r[k];
#pragma unroll
    for (int off = 32; off; off >>= 1) s += __shfl_down(s, off, 64);
    if (lane == 0) d1[row] = s;
}

// in-place row softmax over S=2048 bf16 scores; applies scale and +mask here.
__global__ __launch_bounds__(256)
void softmax_kernel(bf16_t* __restrict__ sc, const float* __restrict__ mask, int S)
{
    const int row = blockIdx.x;
    const int b = row >> 11;             // S = 2048 rows per batch
    bf16_t* p = sc + (size_t)row * S;
    const int tid = threadIdx.x;
    const int w = tid >> 6, lane = tid & 63;
    bf16x8 x = *(const bf16x8*)(p + tid * 8);
    const float4 mk0 = *(const float4*)&mask[(size_t)b * S + tid * 8];
    const float4 mk1 = *(const float4*)&mask[(size_t)b * S + tid * 8 + 4];
    const float mks[8] = {mk0.x, mk0.y, mk0.z, mk0.w, mk1.x, mk1.y, mk1.z, mk1.w};
    float v[8];
    float mx = -1e30f;
#pragma unroll
    for (int j = 0; j < 8; ++j) {
        v[j] = (float)x[j] * 0.03125f + mks[j];   // 1/sqrt(1024), + mask
        mx = fmaxf(mx, v[j]);
    }
#pragma unroll
    for (int off = 32; off; off >>= 1) mx = fmaxf(mx, __shfl_xor(mx, off, 64));
    __shared__ float rmax[4], rsum[4];
    if (lane == 0) rmax[w] = mx;
    __syncthreads();
    mx = fmaxf(fmaxf(rmax[0], rmax[1]), fmaxf(rmax[2], rmax[3]));
    float sum = 0.0f;
#pragma unroll
    for (int j = 0; j < 8; ++j) { v[j] = __expf(v[j] - mx); sum += v[j]; }
#pragma unroll
    for (int off = 32; off; off >>= 1) sum += __shfl_xor(sum, off, 64);
    if (lane == 0) rsum[w] = sum;
    __syncthreads();
    sum = rsum[0] + rsum[1] + rsum[2] + rsum[3];
    const float inv = 1.0f / sum;
    bf16x8 o;
#pragma unroll
    for (int j = 0; j < 8; ++j) o[j] = (__bf16)(v[j] * inv);
    *(bf16x8*)(p + tid * 8) = o;
}

// LayerNorm over H=1024, bf16 in / fp32 out, one block per row
__global__ __launch_bounds__(256)
void ln_kernel(const bf16_t* __restrict__ x, const float* __restrict__ gamma,
               const float* __restrict__ beta, float* __restrict__ out)
{
    const int H = 1024;
    const size_t row = blockIdx.x;
    const int tid = threadIdx.x;
    const int w = tid >> 6, lane = tid & 63;
    bf16x4 xv = *(const bf16x4*)(x + row * H + tid * 4);
    float v[4] = {(float)xv[0], (float)xv[1], (float)xv[2], (float)xv[3]};
    float s = 0.0f, s2 = 0.0f;
#pragma unroll
    for (int j = 0; j < 4; ++j) { s += v[j]; s2 += v[j] * v[j]; }
#pragma unroll
    for (int off = 32; off; off >>= 1) {
        s += __shfl_xor(s, off, 64);
        s2 += __shfl_xor(s2, off, 64);
    }
    __shared__ float rs[4], rs2[4];
    if (lane == 0) { rs[w] = s; rs2[w] = s2; }
    __syncthreads();
    s  = rs[0] + rs[1] + rs[2] + rs[3];
    s2 = rs2[0] + rs2[1] + rs2[2] + rs2[3];
    const float mu  = s * (1.0f / H);
    const float var = s2 * (1.0f / H) - mu * mu;
    const float inv = rsqrtf(var + 1e-12f);
    float4 o;
    const int c = tid * 4;
    o.x = (v[0] - mu) * inv * gamma[c + 0] + beta[c + 0];
    o.y = (v[1] - mu) * inv * gamma[c + 1] + beta[c + 1];
    o.z = (v[2] - mu) * inv * gamma[c + 2] + beta[c + 2];
    o.w = (v[3] - mu) * inv * gamma[c + 3] + beta[c + 3];
    *(float4*)(out + row * H + tid * 4) = o;
}

extern "C" void kernel_launch(void* const* d_in, const int* in_sizes, int n_in,
                              void* d_out, int out_size, void* d_ws, size_t ws_size,
                              hipStream_t stream)
{
    constexpr int B = 4, S = 2048, H = 1024;
    const float* hid = (const float*)d_in[0];
    const float* am  = (const float*)d_in[1];
    const int*   rel = (const int*)d_in[2];
    const float* Wq  = (const float*)d_in[3];
    const float* bq  = (const float*)d_in[4];
    const float* Wk  = (const float*)d_in[5];
    const float* bk  = (const float*)d_in[6];
    const float* Wv  = (const float*)d_in[7];
    const float* bv  = (const float*)d_in[8];
    const float* de  = (const float*)d_in[9];
    const float* Wo  = (const float*)d_in[10];
    const float* bo  = (const float*)d_in[11];
    const float* lng = (const float*)d_in[12];
    const float* lnb = (const float*)d_in[13];
    float* out = (float*)d_out;

    char* ws = (char*)d_ws;
    const int n_tok = B * S;                               // 8192
    const size_t MB = 1024 * 1024;
    bf16_t* hidb = (bf16_t*)(ws);                          // 16 MB
    bf16_t* Wqb  = (bf16_t*)(ws + 16 * MB);                // 2 MB each; Wq/Wk/Wv contiguous
    bf16_t* Wkb  = (bf16_t*)(ws + 18 * MB);
    bf16_t* Wvb  = (bf16_t*)(ws + 20 * MB);
    bf16_t* Wob  = (bf16_t*)(ws + 22 * MB);
    bf16_t* qb   = (bf16_t*)(ws + 24 * MB);                // 16 MB; qb/kb contiguous
    bf16_t* kb   = (bf16_t*)(ws + 40 * MB);                // 16 MB
    bf16_t* vT   = (bf16_t*)(ws + 56 * MB);                // 16 MB (B, DH, S)
    bf16_t* ctx  = (bf16_t*)(ws + 72 * MB);                // 16 MB
    bf16_t* sc   = (bf16_t*)(ws + 88 * MB);                // 32 MB (B,S,S)
    bf16_t* xb   = (bf16_t*)(ws + 88 * MB);                // 16 MB, ALIASES sc (sc dead after PV)
    float*  d1   = (float*)(ws + 120 * MB);                // 32 KB

    const dim3 blk(256);
    const int nH2 = H * H;
    cvt_kernel<<<dim3(n_tok * H / 1024), blk, 0, stream>>>(hid, hidb, n_tok * H);
    cvt_kernel<<<dim3(nH2 / 1024), blk, 0, stream>>>(Wq, Wqb, nH2);
    cvt_kernel<<<dim3(nH2 / 1024), blk, 0, stream>>>(Wk, Wkb, nH2);
    cvt_kernel<<<dim3(nH2 / 1024), blk, 0, stream>>>(Wv, Wvb, nH2);
    cvt_kernel<<<dim3(nH2 / 1024), blk, 0, stream>>>(Wo, Wob, nH2);

    // Q + K + V projections fused over z, grouped swizzle (64 m-tiles x 8 n-tiles)
    gemm_bt<0, 1><<<dim3(64 * 8, 1, 3), blk, 0, stream>>>(
        hidb, Wqb, bq, bk, bv, qb, vT, n_tok, H, H,
        0, 0, (long long)n_tok * H,
        nullptr, nullptr, nullptr, S, H);
    d1_kernel<<<dim3(n_tok / 4), blk, 0, stream>>>(qb, de, d1, H);
    // scores = q@k^T + (rel==1)*d1  -> bf16 (scale+mask folded into softmax)
    gemm_bt<2, 0><<<dim3(S / BN, S / BM, B), blk, 0, stream>>>(
        qb, kb, nullptr, nullptr, nullptr, sc, nullptr, S, S, H,
        (long long)S * H, (long long)S * H, (long long)S * S,
        rel, d1, nullptr, S, H);
    softmax_kernel<<<dim3(B * S), blk, 0, stream>>>(sc, am, S);
    // ctx = probs @ v  (16 m-tiles x 8 n-tiles, grouped swizzle)
    gemm_bt<3, 1><<<dim3(16 * 8, 1, B), blk, 0, stream>>>(
        sc, vT, nullptr, nullptr, nullptr, ctx, nullptr, S, H, S,
        (long long)S * S, (long long)H * S, (long long)S * H,
        nullptr, nullptr, nullptr, S, H);
    // attn_out = ctx @ Wo^T + bo; x = attn_out + hidden  (bf16 out, aliases sc)
    gemm_bt<4, 1><<<dim3(64 * 8, 1, 1), blk, 0, stream>>>(
        ctx, Wob, bo, nullptr, nullptr, xb, nullptr, n_tok, H, H, 0, 0, 0,
        nullptr, nullptr, hid, S, H);
    ln_kernel<<<dim3(n_tok), blk, 0, stream>>>(xb, lng, lnb, out);
}

// Round 7
// 375.230 us; speedup vs baseline: 1.0771x; 1.0771x over previous
//
#include <hip/hip_runtime.h>

#define BM 128
#define BN 128
#define BKH 32   // K-half; one barrier pair covers 2 halves (BK=64)

typedef __bf16 bf16x8 __attribute__((ext_vector_type(8)));
typedef __bf16 bf16x4 __attribute__((ext_vector_type(4)));
typedef float f32x4 __attribute__((ext_vector_type(4)));
typedef __bf16 bf16_t;

__device__ __forceinline__ void gl_lds16(const void* g, void* l) {
    __builtin_amdgcn_global_load_lds(
        (const __attribute__((address_space(1))) void*)g,
        (__attribute__((address_space(3))) void*)l, 16, 0, 0);
}

// fp32 -> bf16 conversion for hid + 4 weight matrices in ONE launch.
// blocks [0, 8192)            : hid   (8192*1024 elems)
// blocks [8192 + i*1024, ...) : W[i]  (1024*1024 elems each)
__global__ __launch_bounds__(256)
void cvt_all_kernel(const float* __restrict__ hid,
                    const float* __restrict__ w0, const float* __restrict__ w1,
                    const float* __restrict__ w2, const float* __restrict__ w3,
                    bf16_t* __restrict__ hidb, bf16_t* __restrict__ wb)
{
    const int bid = blockIdx.x;
    const float* src;
    bf16_t* dst;
    size_t off;
    if (bid < 8192) {
        src = hid; dst = hidb; off = (size_t)bid * 1024;
    } else {
        const int i = (bid - 8192) >> 10;
        src = (i == 0) ? w0 : (i == 1) ? w1 : (i == 2) ? w2 : w3;
        dst = wb + (size_t)i * 1024 * 1024;
        off = (size_t)((bid - 8192) & 1023) * 1024;
    }
    const size_t idx = off + threadIdx.x * 4;
    const float4 v = *(const float4*)(src + idx);
    bf16x4 o;
    o[0] = (__bf16)v.x; o[1] = (__bf16)v.y;
    o[2] = (__bf16)v.z; o[3] = (__bf16)v.w;
    *(bf16x4*)(dst + idx) = o;
}

// Generic NT GEMM: C[m,n] = sum_k A[m,k] * Bw[n,k]  (+ epilogue per MODE)
// MODE 0: QKV fused over z: z=0 -> Wq/bq; z=1 -> Wk/bk; z=2 -> Wv/bv transposed
// MODE 3: plain bf16 store, batched z                  [scores, PV]
// MODE 4: + bias[n] + resid[m,n], bf16 out             [out-proj + residual]
// SWIZ=1: 1D x-grid, grouped decode (GM=8): same-XCD blocks share one A-tile.
// SWIZ=0: plain 2D (blockIdx.x = n-tile, blockIdx.y = m-tile).
// K-loop: BK=64 per barrier pair, staged as two BK=32 halves (A0/A1, B0/B1).
// Row-major epilogues go through a per-wave LDS transpose (bf16x8 stores).
template <int MODE, int SWIZ>
__global__ __launch_bounds__(256)
void gemm_bt(const bf16_t* __restrict__ A, const bf16_t* __restrict__ Bw,
             const float* __restrict__ bias, const float* __restrict__ bias2,
             const float* __restrict__ bias3,
             bf16_t* __restrict__ C, bf16_t* __restrict__ C2,
             int M, int N, int K,
             long long sAz, long long sBz, long long sCz,
             const float* __restrict__ resid,
             int Sdim, int DHdim)
{
    const int bz = blockIdx.z;
    const float* bi = bias;
    if (MODE == 0) {
        Bw += (long long)bz * N * K;        // Wq | Wk | Wv contiguous
        bi = (bz == 0) ? bias : (bz == 1 ? bias2 : bias3);
        if (bz < 2) C += (long long)bz * sCz;
    } else {
        A += (long long)bz * sAz;
        Bw += (long long)bz * sBz;
        C += (long long)bz * sCz;
    }

    int m0, n0;
    if (SWIZ) {
        const int num_n = N / BN;
        const int pid = blockIdx.x;
        const int group = 8 * num_n;         // 8 m-tiles per group
        const int g = pid / group;
        m0 = (g * 8 + (pid % 8)) * BM;
        n0 = ((pid % group) / 8) * BN;
    } else {
        m0 = blockIdx.y * BM;
        n0 = blockIdx.x * BN;
    }
    const int tid = threadIdx.x;
    const int w = tid >> 6;          // wave id 0..3
    const int lane = tid & 63;
    const int wr = w >> 1;           // wave row (2x2 wave grid, 64x64 each)
    const int wc = w & 1;
    const int srow = lane >> 2;      // staging: row within 16-row slice
    const int scol = (lane & 3) * 8; // staging: bf16 col offset (16B chunks)
    const int frow = lane & 15;      // fragment m/n index
    const int fk = (lane >> 4) * 8;  // fragment k base

    __shared__ bf16_t smem[4 * BM * BKH];   // 32 KB: A0 | A1 | B0 | B1
    bf16_t* A0 = smem;
    bf16_t* A1 = smem + BM * BKH;
    bf16_t* B0 = smem + 2 * BM * BKH;
    bf16_t* B1 = smem + 3 * BM * BKH;

    f32x4 acc[4][4];
#pragma unroll
    for (int i = 0; i < 4; ++i)
#pragma unroll
        for (int j = 0; j < 4; ++j) acc[i][j] = (f32x4)0.0f;

    for (int k0 = 0; k0 < K; k0 += 2 * BKH) {
#pragma unroll
        for (int i = 0; i < 2; ++i) {
            const int r = i * 64 + w * 16;
            const bf16_t* ga = A + (size_t)(m0 + r + srow) * K + (k0 + scol);
            const bf16_t* gb = Bw + (size_t)(n0 + r + srow) * K + (k0 + scol);
            gl_lds16(ga,        &A0[r * BKH]);
            gl_lds16(ga + BKH,  &A1[r * BKH]);
            gl_lds16(gb,        &B0[r * BKH]);
            gl_lds16(gb + BKH,  &B1[r * BKH]);
        }
        __syncthreads();
#pragma unroll
        for (int h = 0; h < 2; ++h) {
            const bf16_t* Ah = h ? A1 : A0;
            const bf16_t* Bh = h ? B1 : B0;
            bf16x8 af[4], bfv[4];
#pragma unroll
            for (int t = 0; t < 4; ++t) {
                af[t]  = *(const bf16x8*)&Ah[(wr * 64 + t * 16 + frow) * BKH + fk];
                bfv[t] = *(const bf16x8*)&Bh[(wc * 64 + t * 16 + frow) * BKH + fk];
            }
#pragma unroll
            for (int mt = 0; mt < 4; ++mt)
#pragma unroll
                for (int nt = 0; nt < 4; ++nt)
                    acc[mt][nt] = __builtin_amdgcn_mfma_f32_16x16x32_bf16(
                        af[mt], bfv[nt], acc[mt][nt], 0, 0, 0);
        }
        __syncthreads();
    }
    // After the final __syncthreads all LDS reads are drained; smem reusable.

    // C/D layout: col = lane&15, row = (lane>>4)*4 + reg
    const int crow = (lane >> 4) * 4;
    const int ccol = lane & 15;

    if (MODE == 0 && bz == 2) {
        // V projection: transposed store vT[b][n][s]
#pragma unroll
        for (int mt = 0; mt < 4; ++mt) {
            const int mb = m0 + wr * 64 + mt * 16 + crow;
#pragma unroll
            for (int nt = 0; nt < 4; ++nt) {
                const int n = n0 + wc * 64 + nt * 16 + ccol;
                const float bv = bi[n];
                const int b = mb >> 11;      // S = 2048 tokens per batch
                const int s = mb & 2047;
                union { ushort4 u; bf16_t h[4]; } pk;
#pragma unroll
                for (int r = 0; r < 4; ++r) pk.h[r] = (__bf16)(acc[mt][nt][r] + bv);
                *(ushort4*)&C2[(size_t)b * DHdim * Sdim + (size_t)n * Sdim + s] = pk.u;
            }
        }
        return;
    }

    // ---- transpose epilogue ----
    // per-wave private scratch: 16 rows x 72 cols bf16 (2304 B) -> 4 waves = 9216 B
    bf16_t* tw = smem + w * (16 * 72);
    const int r0 = lane >> 3;            // 0..7 : row within 16-slice
    const int cseg = (lane & 7) * 8;     // 8-col segment base

    float bv[4];
    if (MODE == 0 || MODE == 4) {
#pragma unroll
        for (int nt = 0; nt < 4; ++nt)
            bv[nt] = bi[n0 + wc * 64 + nt * 16 + ccol];
    }

#pragma unroll
    for (int mt = 0; mt < 4; ++mt) {
        // scatter this wave's 16x64 slice into LDS (same-wave DS is in-order)
#pragma unroll
        for (int nt = 0; nt < 4; ++nt) {
            const float badd = (MODE == 0 || MODE == 4) ? bv[nt] : 0.0f;
#pragma unroll
            for (int r = 0; r < 4; ++r)
                tw[(crow + r) * 72 + nt * 16 + ccol] = (__bf16)(acc[mt][nt][r] + badd);
        }
        bf16x8 va = *(const bf16x8*)&tw[r0 * 72 + cseg];
        bf16x8 vb = *(const bf16x8*)&tw[(r0 + 8) * 72 + cseg];

        const int gm_a = m0 + wr * 64 + mt * 16 + r0;
        const int gm_b = gm_a + 8;
        const int gn = n0 + wc * 64 + cseg;

        if (MODE == 0 || MODE == 3) {
            *(bf16x8*)&C[(size_t)gm_a * N + gn] = va;
            *(bf16x8*)&C[(size_t)gm_b * N + gn] = vb;
        } else {  // MODE 4: + residual, bf16 out
            const float4 xa0 = *(const float4*)&resid[(size_t)gm_a * N + gn];
            const float4 xa1 = *(const float4*)&resid[(size_t)gm_a * N + gn + 4];
            const float4 xb0 = *(const float4*)&resid[(size_t)gm_b * N + gn];
            const float4 xb1 = *(const float4*)&resid[(size_t)gm_b * N + gn + 4];
            bf16x8 oa, ob;
            oa[0] = (__bf16)((float)va[0] + xa0.x);
            oa[1] = (__bf16)((float)va[1] + xa0.y);
            oa[2] = (__bf16)((float)va[2] + xa0.z);
            oa[3] = (__bf16)((float)va[3] + xa0.w);
            oa[4] = (__bf16)((float)va[4] + xa1.x);
            oa[5] = (__bf16)((float)va[5] + xa1.y);
            oa[6] = (__bf16)((float)va[6] + xa1.z);
            oa[7] = (__bf16)((float)va[7] + xa1.w);
            ob[0] = (__bf16)((float)vb[0] + xb0.x);
            ob[1] = (__bf16)((float)vb[1] + xb0.y);
            ob[2] = (__bf16)((float)vb[2] + xb0.z);
            ob[3] = (__bf16)((float)vb[3] + xb0.w);
            ob[4] = (__bf16)((float)vb[4] + xb1.x);
            ob[5] = (__bf16)((float)vb[5] + xb1.y);
            ob[6] = (__bf16)((float)vb[6] + xb1.z);
            ob[7] = (__bf16)((float)vb[7] + xb1.w);
            *(bf16x8*)&C[(size_t)gm_a * N + gn] = oa;
            *(bf16x8*)&C[(size_t)gm_b * N + gn] = ob;
        }
    }
}

// Fused softmax over S=2048: computes d1 = q[row]·dist_emb[1] in-block, then
// v = s/32 + mask + (rel==1 ? d1/32 : 0), online max/exp/sum, writes probs.
__global__ __launch_bounds__(256)
void softmax_kernel(bf16_t* __restrict__ sc, const int* __restrict__ rel,
                    const bf16_t* __restrict__ q, const float* __restrict__ de,
                    const float* __restrict__ mask)
{
    constexpr int S = 2048, H = 1024;
    const int row = blockIdx.x;
    const int b = row >> 11;             // 2048 rows per batch
    const int tid = threadIdx.x;
    const int w = tid >> 6, lane = tid & 63;
    __shared__ float rd1[4], rmax[4], rsum[4];

    // ---- d1 = q[row,:] . de[1,:] ----
    const bf16x4 q4 = *(const bf16x4*)(q + (size_t)row * H + tid * 4);
    const float4 e4 = *(const float4*)(de + H + tid * 4);
    float pd = (float)q4[0] * e4.x + (float)q4[1] * e4.y
             + (float)q4[2] * e4.z + (float)q4[3] * e4.w;
#pragma unroll
    for (int off = 32; off; off >>= 1) pd += __shfl_xor(pd, off, 64);
    if (lane == 0) rd1[w] = pd;
    __syncthreads();
    const float d1s = (rd1[0] + rd1[1] + rd1[2] + rd1[3]) * 0.03125f;

    bf16_t* p = sc + (size_t)row * S;
    const bf16x8 x = *(const bf16x8*)(p + tid * 8);
    const int4 rl0 = *(const int4*)&rel[(size_t)row * S + tid * 8];
    const int4 rl1 = *(const int4*)&rel[(size_t)row * S + tid * 8 + 4];
    const float4 mk0 = *(const float4*)&mask[(size_t)b * S + tid * 8];
    const float4 mk1 = *(const float4*)&mask[(size_t)b * S + tid * 8 + 4];
    const int rls[8] = {rl0.x, rl0.y, rl0.z, rl0.w, rl1.x, rl1.y, rl1.z, rl1.w};
    const float mks[8] = {mk0.x, mk0.y, mk0.z, mk0.w, mk1.x, mk1.y, mk1.z, mk1.w};
    float v[8];
    float mx = -1e30f;
#pragma unroll
    for (int j = 0; j < 8; ++j) {
        v[j] = (float)x[j] * 0.03125f + mks[j] + (rls[j] == 1 ? d1s : 0.0f);
        mx = fmaxf(mx, v[j]);
    }
#pragma unroll
    for (int off = 32; off; off >>= 1) mx = fmaxf(mx, __shfl_xor(mx, off, 64));
    if (lane == 0) rmax[w] = mx;
    __syncthreads();
    mx = fmaxf(fmaxf(rmax[0], rmax[1]), fmaxf(rmax[2], rmax[3]));
    float sum = 0.0f;
#pragma unroll
    for (int j = 0; j < 8; ++j) { v[j] = __expf(v[j] - mx); sum += v[j]; }
#pragma unroll
    for (int off = 32; off; off >>= 1) sum += __shfl_xor(sum, off, 64);
    if (lane == 0) rsum[w] = sum;
    __syncthreads();
    sum = rsum[0] + rsum[1] + rsum[2] + rsum[3];
    const float inv = 1.0f / sum;
    bf16x8 o;
#pragma unroll
    for (int j = 0; j < 8; ++j) o[j] = (__bf16)(v[j] * inv);
    *(bf16x8*)(p + tid * 8) = o;
}

// LayerNorm over H=1024, bf16 in / fp32 out, one block per row
__global__ __launch_bounds__(256)
void ln_kernel(const bf16_t* __restrict__ x, const float* __restrict__ gamma,
               const float* __restrict__ beta, float* __restrict__ out)
{
    const int H = 1024;
    const size_t row = blockIdx.x;
    const int tid = threadIdx.x;
    const int w = tid >> 6, lane = tid & 63;
    bf16x4 xv = *(const bf16x4*)(x + row * H + tid * 4);
    float v[4] = {(float)xv[0], (float)xv[1], (float)xv[2], (float)xv[3]};
    float s = 0.0f, s2 = 0.0f;
#pragma unroll
    for (int j = 0; j < 4; ++j) { s += v[j]; s2 += v[j] * v[j]; }
#pragma unroll
    for (int off = 32; off; off >>= 1) {
        s += __shfl_xor(s, off, 64);
        s2 += __shfl_xor(s2, off, 64);
    }
    __shared__ float rs[4], rs2[4];
    if (lane == 0) { rs[w] = s; rs2[w] = s2; }
    __syncthreads();
    s  = rs[0] + rs[1] + rs[2] + rs[3];
    s2 = rs2[0] + rs2[1] + rs2[2] + rs2[3];
    const float mu  = s * (1.0f / H);
    const float var = s2 * (1.0f / H) - mu * mu;
    const float inv = rsqrtf(var + 1e-12f);
    float4 o;
    const int c = tid * 4;
    o.x = (v[0] - mu) * inv * gamma[c + 0] + beta[c + 0];
    o.y = (v[1] - mu) * inv * gamma[c + 1] + beta[c + 1];
    o.z = (v[2] - mu) * inv * gamma[c + 2] + beta[c + 2];
    o.w = (v[3] - mu) * inv * gamma[c + 3] + beta[c + 3];
    *(float4*)(out + row * H + tid * 4) = o;
}

extern "C" void kernel_launch(void* const* d_in, const int* in_sizes, int n_in,
                              void* d_out, int out_size, void* d_ws, size_t ws_size,
                              hipStream_t stream)
{
    constexpr int B = 4, S = 2048, H = 1024;
    const float* hid = (const float*)d_in[0];
    const float* am  = (const float*)d_in[1];
    const int*   rel = (const int*)d_in[2];
    const float* Wq  = (const float*)d_in[3];
    const float* bq  = (const float*)d_in[4];
    const float* Wk  = (const float*)d_in[5];
    const float* bk  = (const float*)d_in[6];
    const float* Wv  = (const float*)d_in[7];
    const float* bv  = (const float*)d_in[8];
    const float* de  = (const float*)d_in[9];
    const float* Wo  = (const float*)d_in[10];
    const float* bo  = (const float*)d_in[11];
    const float* lng = (const float*)d_in[12];
    const float* lnb = (const float*)d_in[13];
    float* out = (float*)d_out;

    char* ws = (char*)d_ws;
    const int n_tok = B * S;                               // 8192
    const size_t MB = 1024 * 1024;
    bf16_t* hidb = (bf16_t*)(ws);                          // 16 MB
    bf16_t* Wqb  = (bf16_t*)(ws + 16 * MB);                // 2 MB each; Wq/Wk/Wv/Wo contiguous
    bf16_t* Wob  = (bf16_t*)(ws + 22 * MB);
    bf16_t* qb   = (bf16_t*)(ws + 24 * MB);                // 16 MB; qb/kb contiguous
    bf16_t* kb   = (bf16_t*)(ws + 40 * MB);                // 16 MB
    bf16_t* vT   = (bf16_t*)(ws + 56 * MB);                // 16 MB (B, DH, S)
    bf16_t* ctx  = (bf16_t*)(ws + 72 * MB);                // 16 MB
    bf16_t* sc   = (bf16_t*)(ws + 88 * MB);                // 32 MB (B,S,S)
    bf16_t* xb   = (bf16_t*)(ws + 88 * MB);                // 16 MB, ALIASES sc (sc dead after PV)

    const dim3 blk(256);
    // hid + Wq/Wk/Wv/Wo fp32->bf16 in one launch (weights contiguous at Wqb)
    cvt_all_kernel<<<dim3(8192 + 4 * 1024), blk, 0, stream>>>(
        hid, Wq, Wk, Wv, Wo, hidb, Wqb);

    // Q + K + V projections fused over z, grouped swizzle (64 m-tiles x 8 n-tiles)
    gemm_bt<0, 1><<<dim3(64 * 8, 1, 3), blk, 0, stream>>>(
        hidb, Wqb, bq, bk, bv, qb, vT, n_tok, H, H,
        0, 0, (long long)n_tok * H,
        nullptr, S, H);
    // scores = q@k^T  (pure GEMM; rel/d1/scale/mask applied in softmax)
    gemm_bt<3, 0><<<dim3(S / BN, S / BM, B), blk, 0, stream>>>(
        qb, kb, nullptr, nullptr, nullptr, sc, nullptr, S, S, H,
        (long long)S * H, (long long)S * H, (long long)S * S,
        nullptr, S, H);
    softmax_kernel<<<dim3(B * S), blk, 0, stream>>>(sc, rel, qb, de, am);
    // ctx = probs @ v  (2D grid — measured best)
    gemm_bt<3, 0><<<dim3(H / BN, S / BM, B), blk, 0, stream>>>(
        sc, vT, nullptr, nullptr, nullptr, ctx, nullptr, S, H, S,
        (long long)S * S, (long long)H * S, (long long)S * H,
        nullptr, S, H);
    // attn_out = ctx @ Wo^T + bo; x = attn_out + hidden  (bf16 out, aliases sc)
    gemm_bt<4, 0><<<dim3(H / BN, n_tok / BM, 1), blk, 0, stream>>>(
        ctx, Wob, bo, nullptr, nullptr, xb, nullptr, n_tok, H, H, 0, 0, 0,
        hid, S, H);
    ln_kernel<<<dim3(n_tok), blk, 0, stream>>>(xb, lng, lnb, out);
}